// Round 4
// baseline (333.075 us; speedup 1.0000x reference)
//
#include <hip/hip_runtime.h>

// Guided filter R=1, EPS=1e-6, (8,3,1024,1024) fp32.
// Barrier-free wave-streaming, zero LDS. Each wave: 248-col x TH-row chunk,
// 4 cols/lane at k0 = c0-4+4l (16B-aligned), float4 loads/stores.
// Lane window is either fully in-range (aligned float4) or fully OOB
// (broadcast edge pixel == replication-pad value its neighbors need).
// Cross-lane +-1 col via DPP WAVE_SHR1/SHL1. Vertical 3-row windows in
// per-lane register rings. Lanes 0 and 63 are pure halo providers
// (own no outputs; their wave-edge DPP garbage is never consumed).
// Doubly-virtual A cols: k0==0 (A(-1):=A(0)) and k0==W-4 (A(W):=A(W-1)).
// Doubly-virtual A rows: ring-slot duplication at top/bottom chunks.

#define NSTRIP 5
#define SOUT 248
#define TH 20
#define NIT (TH + 4)  // 24, multiple of 3

__device__ __forceinline__ float dpp_prev(float v) {  // lane n <- lane n-1
  return __int_as_float(__builtin_amdgcn_update_dpp(
      0, __float_as_int(v), 0x138, 0xF, 0xF, false));  // WAVE_SHR1
}
__device__ __forceinline__ float dpp_next(float v) {  // lane n <- lane n+1
  return __int_as_float(__builtin_amdgcn_update_dpp(
      0, __float_as_int(v), 0x130, 0xF, 0xF, false));  // WAVE_SHL1
}

__global__ __launch_bounds__(256) void gf_kernel(const float* __restrict__ xg,
                                                 const float* __restrict__ yg,
                                                 float* __restrict__ outg,
                                                 const int H, const int W,
                                                 const int nchunk) {
  const int tid = threadIdx.x;
  const int l = tid & 63;
  const int gw = (blockIdx.x << 2) + (tid >> 6);
  const int per_img = NSTRIP * nchunk;
  const int img = gw / per_img;
  const int rem = gw - img * per_img;
  const int chunk = rem / NSTRIP;
  const int strip = rem - chunk * NSTRIP;
  const int c0 = strip * SOUT;                 // multiple of 8
  const int oy0 = min(chunk * TH, H - TH);     // last chunk overlaps (same values)
  const size_t base = (size_t)img * H * W;

  const int k0 = c0 - 4 + 4 * l;               // 16B-aligned window start
  const bool inr = (k0 >= 0) && (k0 <= W - 4); // fully in-range (no straddle: k0%4==0)
  const int cedge = (k0 < 0) ? 0 : (W - 1);    // broadcast col when OOB
  const bool own = (l >= 1) && (l <= 62) && (k0 + 3 <= W - 1);
  const bool eL0 = (k0 == 0);                  // j0 is image col 0
  const bool eR3 = (k0 == W - 4);              // j3 is image col W-1
  const bool tfixw = (oy0 == 0);
  const bool bfixw = (oy0 + TH == H);

  const float inv9 = 1.0f / 9.0f;

  float hx[3][4], hy[3][4], hxy[3][4], hxx[3][4];
  float sa[3][4], sb[3][4], xr3[3][4];
  float nx[4], ny[4];

#define LDROW(RIDX)                                                          \
  {                                                                          \
    const int rn_ = min(max((RIDX), 0), H - 1);                              \
    const float* xr_ = xg + base + (size_t)rn_ * W;                          \
    const float* yr_ = yg + base + (size_t)rn_ * W;                          \
    if (inr) {                                                               \
      const float4 vx_ = *(const float4*)(xr_ + k0);                         \
      const float4 vy_ = *(const float4*)(yr_ + k0);                         \
      nx[0] = vx_.x; nx[1] = vx_.y; nx[2] = vx_.z; nx[3] = vx_.w;            \
      ny[0] = vy_.x; ny[1] = vy_.y; ny[2] = vy_.z; ny[3] = vy_.w;            \
    } else {                                                                 \
      const float sx_ = xr_[cedge], sy_ = yr_[cedge];                        \
      nx[0] = nx[1] = nx[2] = nx[3] = sx_;                                   \
      ny[0] = ny[1] = ny[2] = ny[3] = sy_;                                   \
    }                                                                        \
  }

  LDROW(oy0 - 2)  // preload first row

#define BODY(S, PS, NS, I, DO_A, DO_OUT, DO_TFIX, DO_BFIX)                     \
  {                                                                            \
    const int i_ = (I);                                                        \
    const int rr_ = oy0 - 2 + i_;                                              \
    float cx[4], cy[4];                                                        \
    _Pragma("unroll") for (int j = 0; j < 4; ++j) {                            \
      cx[j] = nx[j];                                                           \
      cy[j] = ny[j];                                                           \
    }                                                                          \
    LDROW(rr_ + 1) /* depth-1 prefetch (last iter re-reads H-1, harmless) */   \
    const float xm_ = dpp_prev(cx[3]), xp_ = dpp_next(cx[0]);                  \
    const float ym_ = dpp_prev(cy[3]), yp_ = dpp_next(cy[0]);                  \
    hx[S][0] = xm_ + cx[0] + cx[1];                                            \
    hy[S][0] = ym_ + cy[0] + cy[1];                                            \
    hxy[S][0] = xm_ * ym_ + cx[0] * cy[0] + cx[1] * cy[1];                     \
    hxx[S][0] = xm_ * xm_ + cx[0] * cx[0] + cx[1] * cx[1];                     \
    hx[S][1] = cx[0] + cx[1] + cx[2];                                          \
    hy[S][1] = cy[0] + cy[1] + cy[2];                                          \
    hxy[S][1] = cx[0] * cy[0] + cx[1] * cy[1] + cx[2] * cy[2];                 \
    hxx[S][1] = cx[0] * cx[0] + cx[1] * cx[1] + cx[2] * cx[2];                 \
    hx[S][2] = cx[1] + cx[2] + cx[3];                                          \
    hy[S][2] = cy[1] + cy[2] + cy[3];                                          \
    hxy[S][2] = cx[1] * cy[1] + cx[2] * cy[2] + cx[3] * cy[3];                 \
    hxx[S][2] = cx[1] * cx[1] + cx[2] * cx[2] + cx[3] * cx[3];                 \
    hx[S][3] = cx[2] + cx[3] + xp_;                                            \
    hy[S][3] = cy[2] + cy[3] + yp_;                                            \
    hxy[S][3] = cx[2] * cy[2] + cx[3] * cy[3] + xp_ * yp_;                     \
    hxx[S][3] = cx[2] * cx[2] + cx[3] * cx[3] + xp_ * xp_;                     \
    _Pragma("unroll") for (int j = 0; j < 4; ++j) xr3[S][j] = cx[j];           \
    if (DO_A) { /* A,b at row rr_-1 */                                         \
      float A_[4], B_[4];                                                      \
      _Pragma("unroll") for (int j = 0; j < 4; ++j) {                          \
        const float Sx = hx[0][j] + hx[1][j] + hx[2][j];                       \
        const float Sy = hy[0][j] + hy[1][j] + hy[2][j];                       \
        const float Sxy = hxy[0][j] + hxy[1][j] + hxy[2][j];                   \
        const float Sxx = hxx[0][j] + hxx[1][j] + hxx[2][j];                   \
        const float mx = Sx * inv9, my = Sy * inv9;                            \
        const float cov = Sxy * inv9 - mx * my;                                \
        const float var = Sxx * inv9 - mx * mx;                                \
        const float d_ = var + 1e-6f;                                          \
        float v_ = __builtin_amdgcn_rcpf(d_);                                  \
        v_ = v_ + v_ * (1.0f - d_ * v_);                                       \
        A_[j] = cov * v_;                                                      \
        B_[j] = my - A_[j] * mx;                                               \
      }                                                                        \
      const float Am_ = dpp_prev(A_[3]), Ap_ = dpp_next(A_[0]);                \
      const float Bm_ = dpp_prev(B_[3]), Bp_ = dpp_next(B_[0]);                \
      sa[S][0] = (eL0 ? A_[0] : Am_) + A_[0] + A_[1];                          \
      sb[S][0] = (eL0 ? B_[0] : Bm_) + B_[0] + B_[1];                          \
      sa[S][1] = A_[0] + A_[1] + A_[2];                                        \
      sb[S][1] = B_[0] + B_[1] + B_[2];                                        \
      sa[S][2] = A_[1] + A_[2] + A_[3];                                        \
      sb[S][2] = B_[1] + B_[2] + B_[3];                                        \
      sa[S][3] = A_[2] + A_[3] + (eR3 ? A_[3] : Ap_);                          \
      sb[S][3] = B_[2] + B_[3] + (eR3 ? B_[3] : Bp_);                          \
      if (DO_TFIX && tfixw) { /* A(-1) := A(0) */                              \
        _Pragma("unroll") for (int j = 0; j < 4; ++j) {                        \
          sa[PS][j] = sa[S][j];                                                \
          sb[PS][j] = sb[S][j];                                                \
        }                                                                      \
      }                                                                        \
      if (DO_BFIX && bfixw) { /* A(H) := A(H-1) */                             \
        _Pragma("unroll") for (int j = 0; j < 4; ++j) {                        \
          sa[S][j] = sa[PS][j];                                                \
          sb[S][j] = sb[PS][j];                                                \
        }                                                                      \
      }                                                                        \
      if (DO_OUT) { /* output row rr_-2 */                                     \
        float o_[4];                                                           \
        _Pragma("unroll") for (int j = 0; j < 4; ++j) {                        \
          const float SA = sa[0][j] + sa[1][j] + sa[2][j];                     \
          const float SB = sb[0][j] + sb[1][j] + sb[2][j];                     \
          const float res = (SA * xr3[NS][j] + SB) * inv9;                     \
          o_[j] = fminf(fmaxf(truncf(res), 0.0f), 255.0f);                     \
        }                                                                      \
        if (own) {                                                             \
          float4 o4_;                                                          \
          o4_.x = o_[0]; o4_.y = o_[1]; o4_.z = o_[2]; o4_.w = o_[3];          \
          *(float4*)(outg + base + (size_t)(rr_ - 2) * W + k0) = o4_;          \
        }                                                                      \
      }                                                                        \
    }                                                                          \
  }

  // prologue: bodies 0..5
  BODY(0, 2, 1, 0, 0, 0, 0, 0)
  BODY(1, 0, 2, 1, 0, 0, 0, 0)
  BODY(2, 1, 0, 2, 1, 0, 0, 0)
  BODY(0, 2, 1, 3, 1, 0, 1, 0)
  BODY(1, 0, 2, 4, 1, 1, 0, 0)
  BODY(2, 1, 0, 5, 1, 1, 0, 0)
  // steady: bodies 6..NIT-4
  for (int ii = 6; ii <= NIT - 6; ii += 3) {
    BODY(0, 2, 1, ii, 1, 1, 0, 0)
    BODY(1, 0, 2, ii + 1, 1, 1, 0, 0)
    BODY(2, 1, 0, ii + 2, 1, 1, 0, 0)
  }
  // epilogue: bodies NIT-3..NIT-1 (bottom fixup on last)
  BODY(0, 2, 1, NIT - 3, 1, 1, 0, 0)
  BODY(1, 0, 2, NIT - 2, 1, 1, 0, 0)
  BODY(2, 1, 0, NIT - 1, 1, 1, 0, 1)
#undef BODY
#undef LDROW
}

extern "C" void kernel_launch(void* const* d_in, const int* in_sizes, int n_in,
                              void* d_out, int out_size, void* d_ws, size_t ws_size,
                              hipStream_t stream) {
  const float* x = (const float*)d_in[0];
  const float* y = (const float*)d_in[1];
  float* out = (float*)d_out;
  const int H = 1024, W = 1024;
  const int imgs = in_sizes[0] / (H * W);      // 24
  const int nchunk = (H + TH - 1) / TH;        // 52
  const int waves = imgs * NSTRIP * nchunk;    // 6240
  dim3 block(256, 1, 1);
  dim3 grid(waves / 4, 1, 1);                  // 1560 blocks, 4 waves each
  gf_kernel<<<grid, block, 0, stream>>>(x, y, out, H, W, nchunk);
}